// Round 1
// baseline (592.249 us; speedup 1.0000x reference)
//
#include <hip/hip_runtime.h>
#include <stdint.h>

typedef __attribute__((ext_vector_type(8))) short short8;
typedef __attribute__((ext_vector_type(4))) float f32x4;

__device__ __forceinline__ uint32_t f2bf1(float f) {
  union { float f; uint32_t u; } c; c.f = f;
  return (c.u + 0x7FFFu + ((c.u >> 16) & 1u)) >> 16;
}
__device__ __forceinline__ uint32_t pack2bf(float lo, float hi) {
  return f2bf1(lo) | (f2bf1(hi) << 16);
}

// ---------------- Phase 1: scatter-add grads[dst] += x[src] * w ------------
// One wave per edge; each lane handles 2 floats (float2).
__global__ void __launch_bounds__(256) scatter_kernel(
    const float* __restrict__ x, const int* __restrict__ src,
    const int* __restrict__ dst, const float* __restrict__ ew,
    float* __restrict__ grads, int E) {
  int e = blockIdx.x * 4 + (threadIdx.x >> 6);
  if (e >= E) return;
  int lane = threadIdx.x & 63;
  int s = src[e];
  int d = dst[e];
  float w = ew[e];
  float2 v = reinterpret_cast<const float2*>(x + (size_t)s * 128)[lane];
  float* g = grads + (size_t)d * 128 + lane * 2;
  unsafeAtomicAdd(g, v.x * w);
  unsafeAtomicAdd(g + 1, v.y * w);
}

// ---------------- Phase 2a: build bf16 cat = [x | normalize(grads)] --------
// One wave per node row (128 elems, 2 per lane).
__global__ void __launch_bounds__(256) catbuild_kernel(
    const float* __restrict__ x, const float* __restrict__ grads,
    uint32_t* __restrict__ cat, int N) {
  int n = blockIdx.x * 4 + (threadIdx.x >> 6);
  if (n >= N) return;
  int lane = threadIdx.x & 63;
  float2 xv = reinterpret_cast<const float2*>(x + (size_t)n * 128)[lane];
  float2 gv = reinterpret_cast<const float2*>(grads + (size_t)n * 128)[lane];
  float ss = gv.x * gv.x + gv.y * gv.y;
  #pragma unroll
  for (int m = 32; m >= 1; m >>= 1) ss += __shfl_xor(ss, m, 64);
  float scale = 1.0f / fmaxf(sqrtf(ss), 1e-12f);
  uint32_t* row = cat + (size_t)n * 128;  // 128 uint32 = 256 bf16
  row[lane]      = pack2bf(xv.x, xv.y);
  row[64 + lane] = pack2bf(gv.x * scale, gv.y * scale);
}

// ---------------- Phase 2a': W (fp32, [128][256]) -> bf16 ------------------
__global__ void __launch_bounds__(256) wconv_kernel(
    const float* __restrict__ W, uint32_t* __restrict__ Wb, int n2) {
  int i = blockIdx.x * 256 + threadIdx.x;  // each packs 2 floats
  if (i < n2) {
    float2 wv = reinterpret_cast<const float2*>(W)[i];
    Wb[i] = pack2bf(wv.x, wv.y);
  }
}

// ---------------- Phase 2b: out = normalize(cat @ W^T + b) -----------------
// One wave per 16-node tile. MFMA 16x16x32 bf16; K=256 (8 steps), N=128 (8 tiles).
// A frag: lane holds cat[node0 + (l&15)][kstep*32 + (l>>4)*8 + 0..7]
// B frag: lane holds W  [ncol*16+(l&15)][kstep*32 + (l>>4)*8 + 0..7]  (B = W^T)
// D frag: lane holds D[(l>>4)*4 + reg][ntile*16 + (l&15)]
__global__ void __launch_bounds__(256) gemm_kernel(
    const ushort* __restrict__ cat, const ushort* __restrict__ Wb,
    const float* __restrict__ bias, float* __restrict__ out, int N) {
  int wid = threadIdx.x >> 6;
  int lane = threadIdx.x & 63;
  int node0 = (blockIdx.x * 4 + wid) * 16;
  if (node0 >= N) return;
  int r = lane & 15;
  int kg = lane >> 4;

  short8 a[8];
  const ushort* arow = cat + (size_t)(node0 + r) * 256 + kg * 8;
  #pragma unroll
  for (int ks = 0; ks < 8; ++ks)
    a[ks] = *reinterpret_cast<const short8*>(arow + ks * 32);

  f32x4 acc[8];
  #pragma unroll
  for (int nt = 0; nt < 8; ++nt) acc[nt] = (f32x4){0.f, 0.f, 0.f, 0.f};

  const ushort* wbase = Wb + kg * 8;
  #pragma unroll
  for (int nt = 0; nt < 8; ++nt) {
    const ushort* wrow = wbase + (size_t)(nt * 16 + r) * 256;
    #pragma unroll
    for (int ks = 0; ks < 8; ++ks) {
      short8 bfrag = *reinterpret_cast<const short8*>(wrow + ks * 32);
      acc[nt] = __builtin_amdgcn_mfma_f32_16x16x32_bf16(a[ks], bfrag, acc[nt], 0, 0, 0);
    }
  }

  float bv[8];
  #pragma unroll
  for (int nt = 0; nt < 8; ++nt) bv[nt] = bias[nt * 16 + r];

  #pragma unroll
  for (int reg = 0; reg < 4; ++reg) {
    float ss = 0.f;
    #pragma unroll
    for (int nt = 0; nt < 8; ++nt) {
      float v = acc[nt][reg] + bv[nt];
      acc[nt][reg] = v;
      ss += v * v;
    }
    // reduce across the 16 lanes of this kg group (covers all 128 cols)
    ss += __shfl_xor(ss, 1, 64);
    ss += __shfl_xor(ss, 2, 64);
    ss += __shfl_xor(ss, 4, 64);
    ss += __shfl_xor(ss, 8, 64);
    float scale = 1.0f / fmaxf(sqrtf(ss), 1e-12f);
    float* orow = out + (size_t)(node0 + kg * 4 + reg) * 128;
    #pragma unroll
    for (int nt = 0; nt < 8; ++nt)
      orow[nt * 16 + r] = acc[nt][reg] * scale;
  }
}

extern "C" void kernel_launch(void* const* d_in, const int* in_sizes, int n_in,
                              void* d_out, int out_size, void* d_ws, size_t ws_size,
                              hipStream_t stream) {
  const float* x    = (const float*)d_in[0];
  const int*   ei   = (const int*)d_in[1];   // [2, E] -> row0 = src, row1 = dst
  const float* ew   = (const float*)d_in[2];
  const float* W    = (const float*)d_in[3];
  const float* bias = (const float*)d_in[4];
  float* out = (float*)d_out;

  int N = in_sizes[0] / 128;
  int E = in_sizes[1] / 2;

  // workspace: bf16 cat [N][256] then bf16 W [128][256]
  uint32_t* cat = (uint32_t*)d_ws;              // N*128 uint32
  uint32_t* Wb  = cat + (size_t)N * 128;        // 16384 uint32

  // grads accumulates in d_out (fp32 [N][128]); GEMM overwrites it at the end.
  hipMemsetAsync(out, 0, (size_t)N * 128 * sizeof(float), stream);
  scatter_kernel<<<(E + 3) / 4, 256, 0, stream>>>(x, ei, ei + E, ew, out, E);
  catbuild_kernel<<<(N + 3) / 4, 256, 0, stream>>>(x, out, cat, N);
  wconv_kernel<<<(16384 + 255) / 256, 256, 0, stream>>>(W, Wb, 16384);
  gemm_kernel<<<(N / 16 + 3) / 4, 256, 0, stream>>>(
      (const ushort*)cat, (const ushort*)Wb, bias, out, N);
}

// Round 2
// 400.756 us; speedup vs baseline: 1.4778x; 1.4778x over previous
//
#include <hip/hip_runtime.h>
#include <stdint.h>

typedef __attribute__((ext_vector_type(8))) short short8;
typedef __attribute__((ext_vector_type(4))) float f32x4;

__device__ __forceinline__ uint32_t f2bf1(float f) {
  union { float f; uint32_t u; } c; c.f = f;
  return (c.u + 0x7FFFu + ((c.u >> 16) & 1u)) >> 16;
}
__device__ __forceinline__ uint32_t pack2bf(float lo, float hi) {
  return f2bf1(lo) | (f2bf1(hi) << 16);
}

// ---------------- CSR build: degree count -----------------------------------
__global__ void __launch_bounds__(256) count_kernel(
    const int* __restrict__ dst, uint32_t* __restrict__ deg, int E) {
  int e = blockIdx.x * 256 + threadIdx.x;
  if (e < E) atomicAdd(&deg[dst[e]], 1u);
}

// ---------------- CSR build: one-block exclusive scan of deg[N] -> starts ---
__global__ void __launch_bounds__(1024) scan_kernel(
    const uint32_t* __restrict__ deg, uint32_t* __restrict__ starts, int N) {
  __shared__ uint32_t sm[1024];
  int t = threadIdx.x;
  int chunk = (N + 1023) >> 10;
  int lo = t * chunk;
  int hi = min(lo + chunk, N);
  uint32_t s = 0;
  for (int i = lo; i < hi; ++i) s += deg[i];
  sm[t] = s;
  uint32_t v = s;
  __syncthreads();
  #pragma unroll
  for (int off = 1; off < 1024; off <<= 1) {
    uint32_t u = (t >= off) ? sm[t - off] : 0u;
    __syncthreads();
    v += u;
    sm[t] = v;
    __syncthreads();
  }
  uint32_t run = v - s;  // exclusive base for this chunk
  for (int i = lo; i < hi; ++i) { starts[i] = run; run += deg[i]; }
}

// ---------------- CSR build: fill edge-id buckets ---------------------------
__global__ void __launch_bounds__(256) fill_kernel(
    const int* __restrict__ dst, const uint32_t* __restrict__ starts,
    uint32_t* __restrict__ cursor, uint32_t* __restrict__ eid, int E) {
  int e = blockIdx.x * 256 + threadIdx.x;
  if (e < E) {
    int d = dst[e];
    uint32_t pos = atomicAdd(&cursor[d], 1u);
    eid[starts[d] + pos] = (uint32_t)e;
  }
}

// ---------------- Gather + normalize + bf16 cat build -----------------------
// One wave per node: grads_row = sum_{e in in(n)} w_e * x[src_e];
// cat[n] = [bf16(x[n]) | bf16(normalize(grads_row))]
__global__ void __launch_bounds__(256) gather_kernel(
    const float* __restrict__ x, const int* __restrict__ src,
    const float* __restrict__ ew, const uint32_t* __restrict__ eid,
    const uint32_t* __restrict__ starts, const uint32_t* __restrict__ deg,
    uint32_t* __restrict__ cat, int N) {
  int n = blockIdx.x * 4 + (threadIdx.x >> 6);
  if (n >= N) return;
  int lane = threadIdx.x & 63;
  uint32_t base = starts[n];
  uint32_t dn = deg[n];
  float ax = 0.f, ay = 0.f;
  for (uint32_t k = 0; k < dn; ++k) {
    uint32_t e = eid[base + k];
    int s = src[e];
    float w = ew[e];
    float2 xv = reinterpret_cast<const float2*>(x + (size_t)s * 128)[lane];
    ax += w * xv.x;
    ay += w * xv.y;
  }
  float ss = ax * ax + ay * ay;
  #pragma unroll
  for (int m = 32; m >= 1; m >>= 1) ss += __shfl_xor(ss, m, 64);
  float scale = 1.0f / fmaxf(sqrtf(ss), 1e-12f);
  float2 xn = reinterpret_cast<const float2*>(x + (size_t)n * 128)[lane];
  uint32_t* row = cat + (size_t)n * 128;  // 128 u32 = 256 bf16
  row[lane]      = pack2bf(xn.x, xn.y);
  row[64 + lane] = pack2bf(ax * scale, ay * scale);
}

// ---------------- W (fp32 [128][256]) -> bf16 -------------------------------
__global__ void __launch_bounds__(256) wconv_kernel(
    const float* __restrict__ W, uint32_t* __restrict__ Wb, int n2) {
  int i = blockIdx.x * 256 + threadIdx.x;
  if (i < n2) {
    float2 wv = reinterpret_cast<const float2*>(W)[i];
    Wb[i] = pack2bf(wv.x, wv.y);
  }
}

// ---------------- out = normalize(cat @ W^T + b) ----------------------------
// One wave per 16-node tile. MFMA 16x16x32 bf16; K=256 (8 steps), N=128 (8 tiles).
__global__ void __launch_bounds__(256) gemm_kernel(
    const ushort* __restrict__ cat, const ushort* __restrict__ Wb,
    const float* __restrict__ bias, float* __restrict__ out, int N) {
  int wid = threadIdx.x >> 6;
  int lane = threadIdx.x & 63;
  int node0 = (blockIdx.x * 4 + wid) * 16;
  if (node0 >= N) return;
  int r = lane & 15;
  int kg = lane >> 4;

  short8 a[8];
  const ushort* arow = cat + (size_t)(node0 + r) * 256 + kg * 8;
  #pragma unroll
  for (int ks = 0; ks < 8; ++ks)
    a[ks] = *reinterpret_cast<const short8*>(arow + ks * 32);

  f32x4 acc[8];
  #pragma unroll
  for (int nt = 0; nt < 8; ++nt) acc[nt] = (f32x4){0.f, 0.f, 0.f, 0.f};

  const ushort* wbase = Wb + kg * 8;
  #pragma unroll
  for (int nt = 0; nt < 8; ++nt) {
    const ushort* wrow = wbase + (size_t)(nt * 16 + r) * 256;
    #pragma unroll
    for (int ks = 0; ks < 8; ++ks) {
      short8 bfrag = *reinterpret_cast<const short8*>(wrow + ks * 32);
      acc[nt] = __builtin_amdgcn_mfma_f32_16x16x32_bf16(a[ks], bfrag, acc[nt], 0, 0, 0);
    }
  }

  float bv[8];
  #pragma unroll
  for (int nt = 0; nt < 8; ++nt) bv[nt] = bias[nt * 16 + r];

  #pragma unroll
  for (int reg = 0; reg < 4; ++reg) {
    float ss = 0.f;
    #pragma unroll
    for (int nt = 0; nt < 8; ++nt) {
      float v = acc[nt][reg] + bv[nt];
      acc[nt][reg] = v;
      ss += v * v;
    }
    ss += __shfl_xor(ss, 1, 64);
    ss += __shfl_xor(ss, 2, 64);
    ss += __shfl_xor(ss, 4, 64);
    ss += __shfl_xor(ss, 8, 64);
    float scale = 1.0f / fmaxf(sqrtf(ss), 1e-12f);
    float* orow = out + (size_t)(node0 + kg * 4 + reg) * 128;
    #pragma unroll
    for (int nt = 0; nt < 8; ++nt)
      orow[nt * 16 + r] = acc[nt][reg] * scale;
  }
}

extern "C" void kernel_launch(void* const* d_in, const int* in_sizes, int n_in,
                              void* d_out, int out_size, void* d_ws, size_t ws_size,
                              hipStream_t stream) {
  const float* x    = (const float*)d_in[0];
  const int*   ei   = (const int*)d_in[1];   // [2, E]: row0 = src, row1 = dst
  const float* ew   = (const float*)d_in[2];
  const float* W    = (const float*)d_in[3];
  const float* bias = (const float*)d_in[4];
  float* out = (float*)d_out;

  int N = in_sizes[0] / 128;
  int E = in_sizes[1] / 2;
  const int* src = ei;
  const int* dst = ei + E;

  // d_ws layout: bf16 cat [N][256] (N*128 u32), then bf16 W (16384 u32)
  uint32_t* cat = (uint32_t*)d_ws;
  uint32_t* Wb  = cat + (size_t)N * 128;

  // CSR scratch lives in d_out (free until gemm overwrites all of d_out):
  // deg[N], cursor[N], starts[N], eid[E]  -> (3N + E) u32 = ~14.5 MB << 51 MB
  uint32_t* o      = (uint32_t*)d_out;
  uint32_t* deg    = o;
  uint32_t* cursor = o + N;
  uint32_t* starts = o + 2 * (size_t)N;
  uint32_t* eidb   = o + 3 * (size_t)N + 16;

  hipMemsetAsync(deg, 0, 2 * (size_t)N * sizeof(uint32_t), stream);  // deg+cursor
  count_kernel<<<(E + 255) / 256, 256, 0, stream>>>(dst, deg, E);
  scan_kernel<<<1, 1024, 0, stream>>>(deg, starts, N);
  fill_kernel<<<(E + 255) / 256, 256, 0, stream>>>(dst, starts, cursor, eidb, E);
  gather_kernel<<<(N + 3) / 4, 256, 0, stream>>>(x, src, ew, eidb, starts, deg, cat, N);
  wconv_kernel<<<(16384 + 255) / 256, 256, 0, stream>>>(W, Wb, 16384);
  gemm_kernel<<<(N / 16 + 3) / 4, 256, 0, stream>>>(
      (const ushort*)cat, (const ushort*)Wb, bias, out, N);
}

// Round 3
// 222.911 us; speedup vs baseline: 2.6569x; 1.7978x over previous
//
#include <hip/hip_runtime.h>
#include <stdint.h>

typedef __attribute__((ext_vector_type(8))) short short8;
typedef __attribute__((ext_vector_type(4))) float f32x4;

__device__ __forceinline__ uint32_t f2bf1(float f) {
  union { float f; uint32_t u; } c; c.f = f;
  return (c.u + 0x7FFFu + ((c.u >> 16) & 1u)) >> 16;
}
__device__ __forceinline__ uint32_t pack2bf(float lo, float hi) {
  return f2bf1(lo) | (f2bf1(hi) << 16);
}

// ---------------- CSR build: degree count -----------------------------------
__global__ void __launch_bounds__(256) count_kernel(
    const int* __restrict__ dst, uint32_t* __restrict__ deg, int E) {
  int e = blockIdx.x * 256 + threadIdx.x;
  if (e < E) atomicAdd(&deg[dst[e]], 1u);
}

// ---------------- scan stage 1: per-1024-chunk exclusive partials -----------
// block b handles deg[b*1024 .. b*1024+1023]; 256 threads x 4 elems each.
__global__ void __launch_bounds__(256) scan1_kernel(
    const uint32_t* __restrict__ deg, uint32_t* __restrict__ partial,
    uint32_t* __restrict__ bsum, int N) {
  __shared__ uint32_t sm[256];
  int t = threadIdx.x;
  int base = blockIdx.x * 1024 + t * 4;
  uint32_t d0 = 0, d1 = 0, d2 = 0, d3 = 0;
  if (base + 3 < N) {
    uint4 v = *reinterpret_cast<const uint4*>(deg + base);
    d0 = v.x; d1 = v.y; d2 = v.z; d3 = v.w;
  } else {
    if (base + 0 < N) d0 = deg[base + 0];
    if (base + 1 < N) d1 = deg[base + 1];
    if (base + 2 < N) d2 = deg[base + 2];
    if (base + 3 < N) d3 = deg[base + 3];
  }
  uint32_t s4 = d0 + d1 + d2 + d3;
  sm[t] = s4;
  uint32_t v = s4;
  __syncthreads();
  #pragma unroll
  for (int off = 1; off < 256; off <<= 1) {
    uint32_t u = (t >= off) ? sm[t - off] : 0u;
    __syncthreads();
    v += u;
    sm[t] = v;
    __syncthreads();
  }
  uint32_t ex = v - s4;  // exclusive within block
  if (base + 0 < N) partial[base + 0] = ex;
  if (base + 1 < N) partial[base + 1] = ex + d0;
  if (base + 2 < N) partial[base + 2] = ex + d0 + d1;
  if (base + 3 < N) partial[base + 3] = ex + d0 + d1 + d2;
  if (t == 255) bsum[blockIdx.x] = v;  // block total
}

// ---------------- scan stage 2: exclusive scan of block sums ----------------
__global__ void __launch_bounds__(1024) scan2_kernel(
    const uint32_t* __restrict__ bsum, uint32_t* __restrict__ boff, int nb) {
  __shared__ uint32_t sm[1024];
  int t = threadIdx.x;
  uint32_t s = (t < nb) ? bsum[t] : 0u;
  sm[t] = s;
  uint32_t v = s;
  __syncthreads();
  #pragma unroll
  for (int off = 1; off < 1024; off <<= 1) {
    uint32_t u = (t >= off) ? sm[t - off] : 0u;
    __syncthreads();
    v += u;
    sm[t] = v;
    __syncthreads();
  }
  if (t < nb) boff[t] = v - s;
}

// ---------------- CSR build: fill (src, weight) pairs -----------------------
__global__ void __launch_bounds__(256) fill_kernel(
    const int* __restrict__ src, const int* __restrict__ dst,
    const float* __restrict__ ew, const uint32_t* __restrict__ partial,
    const uint32_t* __restrict__ boff, uint32_t* __restrict__ cursor,
    uint2* __restrict__ pairs, int E) {
  int e = blockIdx.x * 256 + threadIdx.x;
  if (e < E) {
    int d = dst[e];
    uint32_t pos = atomicAdd(&cursor[d], 1u);
    union { float f; uint32_t u; } w; w.f = ew[e];
    pairs[partial[d] + boff[d >> 10] + pos] = make_uint2((uint32_t)src[e], w.u);
  }
}

// ---------------- Gather + normalize + bf16 cat build -----------------------
__global__ void __launch_bounds__(256) gather_kernel(
    const float* __restrict__ x, const uint2* __restrict__ pairs,
    const uint32_t* __restrict__ partial, const uint32_t* __restrict__ boff,
    const uint32_t* __restrict__ deg, uint32_t* __restrict__ cat, int N) {
  int n = blockIdx.x * 4 + (threadIdx.x >> 6);
  if (n >= N) return;
  int lane = threadIdx.x & 63;
  uint32_t base = partial[n] + boff[n >> 10];
  uint32_t dn = deg[n];
  float ax = 0.f, ay = 0.f;
  for (uint32_t k = 0; k < dn; ++k) {
    uint2 p = pairs[base + k];
    union { uint32_t u; float f; } w; w.u = p.y;
    float2 xv = reinterpret_cast<const float2*>(x + (size_t)p.x * 128)[lane];
    ax += w.f * xv.x;
    ay += w.f * xv.y;
  }
  float ss = ax * ax + ay * ay;
  #pragma unroll
  for (int m = 32; m >= 1; m >>= 1) ss += __shfl_xor(ss, m, 64);
  float scale = 1.0f / fmaxf(sqrtf(ss), 1e-12f);
  float2 xn = reinterpret_cast<const float2*>(x + (size_t)n * 128)[lane];
  uint32_t* row = cat + (size_t)n * 128;  // 128 u32 = 256 bf16
  row[lane]      = pack2bf(xn.x, xn.y);
  row[64 + lane] = pack2bf(ax * scale, ay * scale);
}

// ---------------- W (fp32 [128][256]) -> bf16 -------------------------------
__global__ void __launch_bounds__(256) wconv_kernel(
    const float* __restrict__ W, uint32_t* __restrict__ Wb, int n2) {
  int i = blockIdx.x * 256 + threadIdx.x;
  if (i < n2) {
    float2 wv = reinterpret_cast<const float2*>(W)[i];
    Wb[i] = pack2bf(wv.x, wv.y);
  }
}

// ---------------- out = normalize(cat @ W^T + b) ----------------------------
// One wave per 16-node tile. MFMA 16x16x32 bf16; K=256 (8 steps), N=128 (8 tiles).
__global__ void __launch_bounds__(256) gemm_kernel(
    const ushort* __restrict__ cat, const ushort* __restrict__ Wb,
    const float* __restrict__ bias, float* __restrict__ out, int N) {
  int wid = threadIdx.x >> 6;
  int lane = threadIdx.x & 63;
  int node0 = (blockIdx.x * 4 + wid) * 16;
  if (node0 >= N) return;
  int r = lane & 15;
  int kg = lane >> 4;

  short8 a[8];
  const ushort* arow = cat + (size_t)(node0 + r) * 256 + kg * 8;
  #pragma unroll
  for (int ks = 0; ks < 8; ++ks)
    a[ks] = *reinterpret_cast<const short8*>(arow + ks * 32);

  f32x4 acc[8];
  #pragma unroll
  for (int nt = 0; nt < 8; ++nt) acc[nt] = (f32x4){0.f, 0.f, 0.f, 0.f};

  const ushort* wbase = Wb + kg * 8;
  #pragma unroll
  for (int nt = 0; nt < 8; ++nt) {
    const ushort* wrow = wbase + (size_t)(nt * 16 + r) * 256;
    #pragma unroll
    for (int ks = 0; ks < 8; ++ks) {
      short8 bfrag = *reinterpret_cast<const short8*>(wrow + ks * 32);
      acc[nt] = __builtin_amdgcn_mfma_f32_16x16x32_bf16(a[ks], bfrag, acc[nt], 0, 0, 0);
    }
  }

  float bv[8];
  #pragma unroll
  for (int nt = 0; nt < 8; ++nt) bv[nt] = bias[nt * 16 + r];

  #pragma unroll
  for (int reg = 0; reg < 4; ++reg) {
    float ss = 0.f;
    #pragma unroll
    for (int nt = 0; nt < 8; ++nt) {
      float v = acc[nt][reg] + bv[nt];
      acc[nt][reg] = v;
      ss += v * v;
    }
    ss += __shfl_xor(ss, 1, 64);
    ss += __shfl_xor(ss, 2, 64);
    ss += __shfl_xor(ss, 4, 64);
    ss += __shfl_xor(ss, 8, 64);
    float scale = 1.0f / fmaxf(sqrtf(ss), 1e-12f);
    float* orow = out + (size_t)(node0 + kg * 4 + reg) * 128;
    #pragma unroll
    for (int nt = 0; nt < 8; ++nt)
      orow[nt * 16 + r] = acc[nt][reg] * scale;
  }
}

extern "C" void kernel_launch(void* const* d_in, const int* in_sizes, int n_in,
                              void* d_out, int out_size, void* d_ws, size_t ws_size,
                              hipStream_t stream) {
  const float* x    = (const float*)d_in[0];
  const int*   ei   = (const int*)d_in[1];   // [2, E]: row0 = src, row1 = dst
  const float* ew   = (const float*)d_in[2];
  const float* W    = (const float*)d_in[3];
  const float* bias = (const float*)d_in[4];
  float* out = (float*)d_out;

  int N = in_sizes[0] / 128;
  int E = in_sizes[1] / 2;
  const int* src = ei;
  const int* dst = ei + E;
  int nb = (N + 1023) / 1024;

  // d_ws: bf16 cat [N][256] (N*128 u32), then bf16 W (16384 u32)
  uint32_t* cat = (uint32_t*)d_ws;
  uint32_t* Wb  = cat + (size_t)N * 128;

  // CSR scratch in d_out (free until gemm overwrites d_out):
  // deg[N], cursor[N], partial[N], boff[nb(pad 1024)], pairs[E] (uint2)
  uint32_t* o       = (uint32_t*)d_out;
  uint32_t* deg     = o;
  uint32_t* cursor  = o + N;
  uint32_t* partial = o + 2 * (size_t)N;
  uint32_t* bsum    = o + 3 * (size_t)N;
  uint32_t* boff    = o + 3 * (size_t)N + 1024;
  uint2*    pairs   = (uint2*)(o + 3 * (size_t)N + 2048);

  hipMemsetAsync(deg, 0, 2 * (size_t)N * sizeof(uint32_t), stream);  // deg+cursor
  count_kernel<<<(E + 255) / 256, 256, 0, stream>>>(dst, deg, E);
  scan1_kernel<<<nb, 256, 0, stream>>>(deg, partial, bsum, N);
  scan2_kernel<<<1, 1024, 0, stream>>>(bsum, boff, nb);
  fill_kernel<<<(E + 255) / 256, 256, 0, stream>>>(src, dst, ew, partial, boff,
                                                   cursor, pairs, E);
  gather_kernel<<<(N + 3) / 4, 256, 0, stream>>>(x, pairs, partial, boff, deg, cat, N);
  wconv_kernel<<<(16384 + 255) / 256, 256, 0, stream>>>(W, Wb, 16384);
  gemm_kernel<<<(N / 16 + 3) / 4, 256, 0, stream>>>(
      (const ushort*)cat, (const ushort*)Wb, bias, out, N);
}

// Round 4
// 207.831 us; speedup vs baseline: 2.8497x; 1.0726x over previous
//
#include <hip/hip_runtime.h>
#include <stdint.h>

typedef __attribute__((ext_vector_type(8))) short short8;
typedef __attribute__((ext_vector_type(4))) float f32x4;

__device__ __forceinline__ uint32_t f2bf1(float f) {
  union { float f; uint32_t u; } c; c.f = f;
  return (c.u + 0x7FFFu + ((c.u >> 16) & 1u)) >> 16;
}
__device__ __forceinline__ uint32_t pack2bf(float lo, float hi) {
  return f2bf1(lo) | (f2bf1(hi) << 16);
}
__device__ __forceinline__ float bflo(uint32_t u) {
  union { uint32_t u; float f; } c; c.u = u << 16; return c.f;
}
__device__ __forceinline__ float bfhi(uint32_t u) {
  union { uint32_t u; float f; } c; c.u = u & 0xFFFF0000u; return c.f;
}

// ---------------- CSR build: degree count -----------------------------------
__global__ void __launch_bounds__(256) count_kernel(
    const int* __restrict__ dst, uint32_t* __restrict__ deg, int E) {
  int e = blockIdx.x * 256 + threadIdx.x;
  if (e < E) atomicAdd(&deg[dst[e]], 1u);
}

// ---------------- scan stage 1: per-1024-chunk exclusive partials -----------
__global__ void __launch_bounds__(256) scan1_kernel(
    const uint32_t* __restrict__ deg, uint32_t* __restrict__ partial,
    uint32_t* __restrict__ bsum, int N) {
  __shared__ uint32_t sm[256];
  int t = threadIdx.x;
  int base = blockIdx.x * 1024 + t * 4;
  uint32_t d0 = 0, d1 = 0, d2 = 0, d3 = 0;
  if (base + 3 < N) {
    uint4 v = *reinterpret_cast<const uint4*>(deg + base);
    d0 = v.x; d1 = v.y; d2 = v.z; d3 = v.w;
  } else {
    if (base + 0 < N) d0 = deg[base + 0];
    if (base + 1 < N) d1 = deg[base + 1];
    if (base + 2 < N) d2 = deg[base + 2];
    if (base + 3 < N) d3 = deg[base + 3];
  }
  uint32_t s4 = d0 + d1 + d2 + d3;
  sm[t] = s4;
  uint32_t v = s4;
  __syncthreads();
  #pragma unroll
  for (int off = 1; off < 256; off <<= 1) {
    uint32_t u = (t >= off) ? sm[t - off] : 0u;
    __syncthreads();
    v += u;
    sm[t] = v;
    __syncthreads();
  }
  uint32_t ex = v - s4;
  if (base + 0 < N) partial[base + 0] = ex;
  if (base + 1 < N) partial[base + 1] = ex + d0;
  if (base + 2 < N) partial[base + 2] = ex + d0 + d1;
  if (base + 3 < N) partial[base + 3] = ex + d0 + d1 + d2;
  if (t == 255) bsum[blockIdx.x] = v;
}

// ---------------- scan stage 2: exclusive scan of block sums ----------------
__global__ void __launch_bounds__(1024) scan2_kernel(
    const uint32_t* __restrict__ bsum, uint32_t* __restrict__ boff, int nb) {
  __shared__ uint32_t sm[1024];
  int t = threadIdx.x;
  uint32_t s = (t < nb) ? bsum[t] : 0u;
  sm[t] = s;
  uint32_t v = s;
  __syncthreads();
  #pragma unroll
  for (int off = 1; off < 1024; off <<= 1) {
    uint32_t u = (t >= off) ? sm[t - off] : 0u;
    __syncthreads();
    v += u;
    sm[t] = v;
    __syncthreads();
  }
  if (t < nb) boff[t] = v - s;
}

// ---------------- CSR build: fill (src, weight) pairs -----------------------
__global__ void __launch_bounds__(256) fill_kernel(
    const int* __restrict__ src, const int* __restrict__ dst,
    const float* __restrict__ ew, const uint32_t* __restrict__ partial,
    const uint32_t* __restrict__ boff, uint32_t* __restrict__ cursor,
    uint2* __restrict__ pairs, int E) {
  int e = blockIdx.x * 256 + threadIdx.x;
  if (e < E) {
    int d = dst[e];
    uint32_t pos = atomicAdd(&cursor[d], 1u);
    union { float f; uint32_t u; } w; w.f = ew[e];
    pairs[partial[d] + boff[d >> 10] + pos] = make_uint2((uint32_t)src[e], w.u);
  }
}

// ---------------- x (fp32) -> bf16 into cat first halves --------------------
__global__ void __launch_bounds__(256) xconv_kernel(
    const float* __restrict__ x, uint32_t* __restrict__ cat, int N) {
  int n = blockIdx.x * 4 + (threadIdx.x >> 6);
  if (n >= N) return;
  int lane = threadIdx.x & 63;
  float2 xv = reinterpret_cast<const float2*>(x + (size_t)n * 128)[lane];
  cat[(size_t)n * 128 + lane] = pack2bf(xv.x, xv.y);
}

// ---------------- Gather (bf16 rows, 2 edges/iter) + normalize --------------
// Lanes 0-31 accumulate even edges, 32-63 odd edges; each lane covers
// elements 4*sl .. 4*sl+3 of the 128-elem row via one uint2 (4 bf16) load.
__global__ void __launch_bounds__(256) gather_kernel(
    const uint2* __restrict__ pairs, const uint32_t* __restrict__ partial,
    const uint32_t* __restrict__ boff, const uint32_t* __restrict__ deg,
    uint32_t* __restrict__ cat, int N) {
  int n = blockIdx.x * 4 + (threadIdx.x >> 6);
  if (n >= N) return;
  int lane = threadIdx.x & 63;
  int half = lane >> 5;
  int sl = lane & 31;
  uint32_t base = partial[n] + boff[n >> 10];
  uint32_t dn = deg[n];
  float a0 = 0.f, a1 = 0.f, a2 = 0.f, a3 = 0.f;
  for (uint32_t k = (uint32_t)half; k < dn; k += 2) {
    uint2 p = pairs[base + k];
    union { uint32_t u; float f; } w; w.u = p.y;
    uint2 v = reinterpret_cast<const uint2*>(cat + (size_t)p.x * 128)[sl];
    a0 += w.f * bflo(v.x);
    a1 += w.f * bfhi(v.x);
    a2 += w.f * bflo(v.y);
    a3 += w.f * bfhi(v.y);
  }
  a0 += __shfl_xor(a0, 32, 64);
  a1 += __shfl_xor(a1, 32, 64);
  a2 += __shfl_xor(a2, 32, 64);
  a3 += __shfl_xor(a3, 32, 64);
  float ss = a0 * a0 + a1 * a1 + a2 * a2 + a3 * a3;
  #pragma unroll
  for (int m = 16; m >= 1; m >>= 1) ss += __shfl_xor(ss, m, 64);
  float scale = 1.0f / fmaxf(sqrtf(ss), 1e-12f);
  if (half == 0) {
    uint2 o;
    o.x = pack2bf(a0 * scale, a1 * scale);
    o.y = pack2bf(a2 * scale, a3 * scale);
    reinterpret_cast<uint2*>(cat + (size_t)n * 128 + 64)[sl] = o;
  }
}

// ---------------- W (fp32 [128][256]) -> bf16 -------------------------------
__global__ void __launch_bounds__(256) wconv_kernel(
    const float* __restrict__ W, uint32_t* __restrict__ Wb, int n2) {
  int i = blockIdx.x * 256 + threadIdx.x;
  if (i < n2) {
    float2 wv = reinterpret_cast<const float2*>(W)[i];
    Wb[i] = pack2bf(wv.x, wv.y);
  }
}

// ---------------- out = normalize(cat @ W^T + b) ----------------------------
__global__ void __launch_bounds__(256) gemm_kernel(
    const ushort* __restrict__ cat, const ushort* __restrict__ Wb,
    const float* __restrict__ bias, float* __restrict__ out, int N) {
  int wid = threadIdx.x >> 6;
  int lane = threadIdx.x & 63;
  int node0 = (blockIdx.x * 4 + wid) * 16;
  if (node0 >= N) return;
  int r = lane & 15;
  int kg = lane >> 4;

  short8 a[8];
  const ushort* arow = cat + (size_t)(node0 + r) * 256 + kg * 8;
  #pragma unroll
  for (int ks = 0; ks < 8; ++ks)
    a[ks] = *reinterpret_cast<const short8*>(arow + ks * 32);

  f32x4 acc[8];
  #pragma unroll
  for (int nt = 0; nt < 8; ++nt) acc[nt] = (f32x4){0.f, 0.f, 0.f, 0.f};

  const ushort* wbase = Wb + kg * 8;
  #pragma unroll
  for (int nt = 0; nt < 8; ++nt) {
    const ushort* wrow = wbase + (size_t)(nt * 16 + r) * 256;
    #pragma unroll
    for (int ks = 0; ks < 8; ++ks) {
      short8 bfrag = *reinterpret_cast<const short8*>(wrow + ks * 32);
      acc[nt] = __builtin_amdgcn_mfma_f32_16x16x32_bf16(a[ks], bfrag, acc[nt], 0, 0, 0);
    }
  }

  float bv[8];
  #pragma unroll
  for (int nt = 0; nt < 8; ++nt) bv[nt] = bias[nt * 16 + r];

  #pragma unroll
  for (int reg = 0; reg < 4; ++reg) {
    float ss = 0.f;
    #pragma unroll
    for (int nt = 0; nt < 8; ++nt) {
      float v = acc[nt][reg] + bv[nt];
      acc[nt][reg] = v;
      ss += v * v;
    }
    ss += __shfl_xor(ss, 1, 64);
    ss += __shfl_xor(ss, 2, 64);
    ss += __shfl_xor(ss, 4, 64);
    ss += __shfl_xor(ss, 8, 64);
    float scale = 1.0f / fmaxf(sqrtf(ss), 1e-12f);
    float* orow = out + (size_t)(node0 + kg * 4 + reg) * 128;
    #pragma unroll
    for (int nt = 0; nt < 8; ++nt)
      orow[nt * 16 + r] = acc[nt][reg] * scale;
  }
}

extern "C" void kernel_launch(void* const* d_in, const int* in_sizes, int n_in,
                              void* d_out, int out_size, void* d_ws, size_t ws_size,
                              hipStream_t stream) {
  const float* x    = (const float*)d_in[0];
  const int*   ei   = (const int*)d_in[1];   // [2, E]: row0 = src, row1 = dst
  const float* ew   = (const float*)d_in[2];
  const float* W    = (const float*)d_in[3];
  const float* bias = (const float*)d_in[4];
  float* out = (float*)d_out;

  int N = in_sizes[0] / 128;
  int E = in_sizes[1] / 2;
  const int* src = ei;
  const int* dst = ei + E;
  int nb = (N + 1023) / 1024;

  // d_ws: bf16 cat [N][256] (N*128 u32), then bf16 W (16384 u32)
  uint32_t* cat = (uint32_t*)d_ws;
  uint32_t* Wb  = cat + (size_t)N * 128;

  // CSR scratch in d_out (free until gemm overwrites d_out):
  uint32_t* o       = (uint32_t*)d_out;
  uint32_t* deg     = o;
  uint32_t* cursor  = o + N;
  uint32_t* partial = o + 2 * (size_t)N;
  uint32_t* bsum    = o + 3 * (size_t)N;
  uint32_t* boff    = o + 3 * (size_t)N + 1024;
  uint2*    pairs   = (uint2*)(o + 3 * (size_t)N + 2048);

  hipMemsetAsync(deg, 0, 2 * (size_t)N * sizeof(uint32_t), stream);  // deg+cursor
  count_kernel<<<(E + 255) / 256, 256, 0, stream>>>(dst, deg, E);
  xconv_kernel<<<(N + 3) / 4, 256, 0, stream>>>(x, cat, N);
  scan1_kernel<<<nb, 256, 0, stream>>>(deg, partial, bsum, N);
  scan2_kernel<<<1, 1024, 0, stream>>>(bsum, boff, nb);
  fill_kernel<<<(E + 255) / 256, 256, 0, stream>>>(src, dst, ew, partial, boff,
                                                   cursor, pairs, E);
  gather_kernel<<<(N + 3) / 4, 256, 0, stream>>>(pairs, partial, boff, deg, cat, N);
  wconv_kernel<<<(16384 + 255) / 256, 256, 0, stream>>>(W, Wb, 16384);
  gemm_kernel<<<(N / 16 + 3) / 4, 256, 0, stream>>>(
      (const ushort*)cat, (const ushort*)Wb, bias, out, N);
}